// Round 8
// baseline (400.067 us; speedup 1.0000x reference)
//
#include <hip/hip_runtime.h>
#include <math.h>

// ---------------------------------------------------------------------------
// GATv2 2-layer GNN, fp32 in/out. N=50000, E=800000, F=128.
//   1. CSR by dst, UNORDERED segments (memset -> count -> atomic offsets ->
//      scatter)
//   2. prep_w: W -> bf16 hi/lo transposed [n][k]; split_x: x -> Xhi/Xlo bf16
//   3. GEMM v4 (split-bf16 MFMA 3-term): staging reads PRE-SPLIT bf16 —
//      no split VALU in the hot loop. Wave = 128 rows x 32 cols.
//   4. aggregate: plain-exp softmax, half-wave float4, 4-pair batches.
//      Layer-1 aggregate emits h directly as bf16 hi/lo (same bytes,
//      identical truncation rounding as the old in-GEMM split).
// ---------------------------------------------------------------------------

typedef short bf16x8 __attribute__((ext_vector_type(8)));
typedef float f32x4 __attribute__((ext_vector_type(4)));

__global__ void count_deg_kernel(const int* __restrict__ dst, int* __restrict__ deg, int E) {
    int i = blockIdx.x * blockDim.x + threadIdx.x;
    if (i < E) atomicAdd(&deg[dst[i]], 1);
}

// Each node gets a disjoint contiguous slice [beg, beg+deg) in arbitrary order.
__global__ void assign_offsets_kernel(int* __restrict__ deg, int* __restrict__ row_beg,
                                      int* __restrict__ writeidx, int n) {
    int i = blockIdx.x * blockDim.x + threadIdx.x;
    if (i < n) {
        int d = deg[i];
        int beg = atomicAdd(&deg[n], d);  // wave-aggregated by compiler
        row_beg[i] = beg;
        writeidx[i] = beg;
    }
}

__global__ void scatter_edges_kernel(const int* __restrict__ src, const int* __restrict__ dst,
                                     int* __restrict__ writeidx, int* __restrict__ csr_src, int E) {
    int i = blockIdx.x * blockDim.x + threadIdx.x;
    if (i < E) {
        int d = dst[i];
        int pos = atomicAdd(&writeidx[d], 1);
        csr_src[pos] = src[i];
    }
}

// ---------------------------------------------------------------------------
// Split each 128x128 fp32 W into bf16 hi/lo, transposed to [n][k].
// ---------------------------------------------------------------------------
__global__ __launch_bounds__(256) void prep_w_kernel(
    const float* __restrict__ W0, const float* __restrict__ W1,
    const float* __restrict__ W2, const float* __restrict__ W3,
    short* __restrict__ wt) {
    int mat = blockIdx.x >> 3;
    int chunk = blockIdx.x & 7;
    const float* W = (mat == 0) ? W0 : (mat == 1) ? W1 : (mat == 2) ? W2 : W3;
    short* hi = wt + (size_t)mat * 2 * 16384;
    short* lo = hi + 16384;
    int i0 = chunk * 2048;
    for (int i = i0 + threadIdx.x; i < i0 + 2048; i += 256) {
        int k = i >> 7, n = i & 127;
        float x = W[i];
        unsigned u = __float_as_uint(x);
        unsigned hu = u & 0xFFFF0000u;
        float lf = x - __uint_as_float(hu);
        hi[n * 128 + k] = (short)(hu >> 16);
        lo[n * 128 + k] = (short)(__float_as_uint(lf) >> 16);
    }
}

// ---------------------------------------------------------------------------
// Split x (fp32 [N][128]) into Xhi/Xlo bf16 [N][128], row-major.
// ---------------------------------------------------------------------------
__global__ __launch_bounds__(256) void split_x_kernel(const float* __restrict__ X,
                                                      short* __restrict__ Xhi,
                                                      short* __restrict__ Xlo, int total4) {
    int i = blockIdx.x * 256 + threadIdx.x;
    if (i >= total4) return;
    float4 v = ((const float4*)X)[i];
    float vv[4] = {v.x, v.y, v.z, v.w};
    short h[4], l[4];
    #pragma unroll
    for (int j = 0; j < 4; ++j) {
        unsigned u = __float_as_uint(vv[j]);
        unsigned hu = u & 0xFFFF0000u;
        float lf = vv[j] - __uint_as_float(hu);
        h[j] = (short)(hu >> 16);
        l[j] = (short)(__float_as_uint(lf) >> 16);
    }
    ((short4*)Xhi)[i] = make_short4(h[0], h[1], h[2], h[3]);
    ((short4*)Xlo)[i] = make_short4(l[0], l[1], l[2], l[3]);
}

// ---------------------------------------------------------------------------
// Split-bf16 MFMA GEMM v4: out = X @ W + b, X pre-split into bf16 hi/lo.
// Block: 256 thr, tile 128(M) x 128(N), K=128 in 4 chunks of 32.
// Wave w owns ALL 128 rows x cols [w*32, w*32+32): 8 m-tiles x 2 n-tiles.
// Staging: pure copy (2 bf16x8 loads + 2 ds_write_b128 per thread per pass).
// ---------------------------------------------------------------------------
__global__ __launch_bounds__(256) void gemm_mfma_dual_kernel(
    const short* __restrict__ Xhi, const short* __restrict__ Xlo,
    const short* __restrict__ wt,
    const float* __restrict__ b0, float* __restrict__ out0,
    const float* __restrict__ b1, float* __restrict__ out1,
    int Nrows) {
    const short* WTh = wt + (size_t)blockIdx.y * 2 * 16384;
    const short* WTl = WTh + 16384;
    const float* bias = blockIdx.y ? b1 : b0;
    float* out = blockIdx.y ? out1 : out0;

    __shared__ short Ahi[128][40];   // stride 80 B (16B-aligned rows)
    __shared__ short Alo[128][40];

    int tid = threadIdx.x;
    int w = tid >> 6, lane = tid & 63, q = lane >> 4, tr = lane & 15;
    int m0 = blockIdx.x * 128;
    int n0 = w * 32;

    f32x4 acc[8][2];
    #pragma unroll
    for (int a = 0; a < 8; ++a)
        #pragma unroll
        for (int b = 0; b < 2; ++b) acc[a][b] = (f32x4){0.f, 0.f, 0.f, 0.f};

    int r0 = tid >> 2;          // 0..63
    int c8 = (tid & 3) * 8;     // 0,8,16,24

    for (int kc = 0; kc < 128; kc += 32) {
        // stage pre-split X tile (128 rows x 32 k), pure copy
        #pragma unroll
        for (int pass = 0; pass < 2; ++pass) {
            int r = r0 + pass * 64;
            int gr = m0 + r; if (gr >= Nrows) gr = Nrows - 1;  // stores guarded later
            size_t goff = (size_t)gr * 128 + kc + c8;
            bf16x8 vh = *(const bf16x8*)&Xhi[goff];
            bf16x8 vl = *(const bf16x8*)&Xlo[goff];
            *(bf16x8*)&Ahi[r][c8] = vh;
            *(bf16x8*)&Alo[r][c8] = vl;
        }
        __syncthreads();

        // B fragments for this wave's 2 n-tiles
        bf16x8 bh[2], bl[2];
        #pragma unroll
        for (int nt = 0; nt < 2; ++nt) {
            size_t boff = (size_t)(n0 + nt * 16 + tr) * 128 + kc + q * 8;
            bh[nt] = *(const bf16x8*)&WTh[boff];
            bl[nt] = *(const bf16x8*)&WTl[boff];
        }

        // A fragments from LDS, 8 m-tiles; A[m = lane&15][k = q*8 + j]
        #pragma unroll
        for (int mt = 0; mt < 8; ++mt) {
            bf16x8 ah = *(const bf16x8*)&Ahi[mt * 16 + tr][q * 8];
            bf16x8 al = *(const bf16x8*)&Alo[mt * 16 + tr][q * 8];
            #pragma unroll
            for (int nt = 0; nt < 2; ++nt) {
                acc[mt][nt] = __builtin_amdgcn_mfma_f32_16x16x32_bf16(ah, bh[nt], acc[mt][nt], 0, 0, 0);
                acc[mt][nt] = __builtin_amdgcn_mfma_f32_16x16x32_bf16(ah, bl[nt], acc[mt][nt], 0, 0, 0);
                acc[mt][nt] = __builtin_amdgcn_mfma_f32_16x16x32_bf16(al, bh[nt], acc[mt][nt], 0, 0, 0);
            }
        }
        __syncthreads();
    }

    // epilogue: D layout col = lane&15, row = q*4 + reg
    #pragma unroll
    for (int nt = 0; nt < 2; ++nt) {
        float bv = bias[n0 + nt * 16 + tr];
        #pragma unroll
        for (int mt = 0; mt < 8; ++mt) {
            #pragma unroll
            for (int r = 0; r < 4; ++r) {
                int row = m0 + mt * 16 + q * 4 + r;
                if (row < Nrows)
                    out[(size_t)row * 128 + n0 + nt * 16 + tr] = acc[mt][nt][r] + bv;
            }
        }
    }
}

// ---------------------------------------------------------------------------
// Aggregation (round-7 core, measured 60.4 us): plain-exp softmax, half-wave
// float4, 4-pair batches + 2/1-pair tail. emitSplit=1: write bf16 hi/lo
// (+relu) for the next GEMM; emitSplit=0: write fp32 to outF.
// ---------------------------------------------------------------------------
__global__ __launch_bounds__(256) void gat_aggregate_kernel(
    const float* __restrict__ xl, const float* __restrict__ xr,
    const float* __restrict__ att, const float* __restrict__ bias,
    const int* __restrict__ row_beg, const int* __restrict__ deg,
    const int* __restrict__ csr_src,
    float* __restrict__ outF, short* __restrict__ outHi, short* __restrict__ outLo,
    int N, int emitSplit) {
    int wid = threadIdx.x >> 6;
    int lane = threadIdx.x & 63;
    int hlane = lane & 31;
    int half = lane >> 5;
    int node = blockIdx.x * 4 + wid;
    if (node >= N) return;

    const float4* xl4 = (const float4*)xl;
    float4 xrv = ((const float4*)xr)[(size_t)node * 32 + hlane];
    float4 attv = ((const float4*)att)[hlane];

    int beg = row_beg[node];
    int end = beg + deg[node];

    float dsum = 0.f;
    float4 acc = {0.f, 0.f, 0.f, 0.f};

    for (int cbase = beg; cbase < end; cbase += 64) {
        int cnt = end - cbase;
        if (cnt > 64) cnt = 64;
        int myidx = (lane < cnt) ? csr_src[cbase + lane] : 0;  // coalesced
        int npair = cnt >> 1;

        int j = 0;
        for (; j + 4 <= npair; j += 4) {
            int b0 = 2 * j + half;
            int s0 = __shfl(myidx, b0 + 0);
            int s1 = __shfl(myidx, b0 + 2);
            int s2 = __shfl(myidx, b0 + 4);
            int s3 = __shfl(myidx, b0 + 6);
            float4 v0 = xl4[(size_t)s0 * 32 + hlane];
            float4 v1 = xl4[(size_t)s1 * 32 + hlane];
            float4 v2 = xl4[(size_t)s2 * 32 + hlane];
            float4 v3 = xl4[(size_t)s3 * 32 + hlane];

            float t, p0, p1, p2, p3;
            t = v0.x + xrv.x; t = t > 0.f ? t : 0.2f * t; p0 = t * attv.x;
            t = v0.y + xrv.y; t = t > 0.f ? t : 0.2f * t; p0 = fmaf(t, attv.y, p0);
            t = v0.z + xrv.z; t = t > 0.f ? t : 0.2f * t; p0 = fmaf(t, attv.z, p0);
            t = v0.w + xrv.w; t = t > 0.f ? t : 0.2f * t; p0 = fmaf(t, attv.w, p0);
            t = v1.x + xrv.x; t = t > 0.f ? t : 0.2f * t; p1 = t * attv.x;
            t = v1.y + xrv.y; t = t > 0.f ? t : 0.2f * t; p1 = fmaf(t, attv.y, p1);
            t = v1.z + xrv.z; t = t > 0.f ? t : 0.2f * t; p1 = fmaf(t, attv.z, p1);
            t = v1.w + xrv.w; t = t > 0.f ? t : 0.2f * t; p1 = fmaf(t, attv.w, p1);
            t = v2.x + xrv.x; t = t > 0.f ? t : 0.2f * t; p2 = t * attv.x;
            t = v2.y + xrv.y; t = t > 0.f ? t : 0.2f * t; p2 = fmaf(t, attv.y, p2);
            t = v2.z + xrv.z; t = t > 0.f ? t : 0.2f * t; p2 = fmaf(t, attv.z, p2);
            t = v2.w + xrv.w; t = t > 0.f ? t : 0.2f * t; p2 = fmaf(t, attv.w, p2);
            t = v3.x + xrv.x; t = t > 0.f ? t : 0.2f * t; p3 = t * attv.x;
            t = v3.y + xrv.y; t = t > 0.f ? t : 0.2f * t; p3 = fmaf(t, attv.y, p3);
            t = v3.z + xrv.z; t = t > 0.f ? t : 0.2f * t; p3 = fmaf(t, attv.z, p3);
            t = v3.w + xrv.w; t = t > 0.f ? t : 0.2f * t; p3 = fmaf(t, attv.w, p3);

            #pragma unroll
            for (int off = 16; off > 0; off >>= 1) {
                p0 += __shfl_xor(p0, off);
                p1 += __shfl_xor(p1, off);
                p2 += __shfl_xor(p2, off);
                p3 += __shfl_xor(p3, off);
            }

            float e0 = __expf(p0);
            float e1 = __expf(p1);
            float e2 = __expf(p2);
            float e3 = __expf(p3);
            dsum += (e0 + e1) + (e2 + e3);
            acc.x = fmaf(e3, v3.x, fmaf(e2, v2.x, fmaf(e1, v1.x, fmaf(e0, v0.x, acc.x))));
            acc.y = fmaf(e3, v3.y, fmaf(e2, v2.y, fmaf(e1, v1.y, fmaf(e0, v0.y, acc.y))));
            acc.z = fmaf(e3, v3.z, fmaf(e2, v2.z, fmaf(e1, v1.z, fmaf(e0, v0.z, acc.z))));
            acc.w = fmaf(e3, v3.w, fmaf(e2, v2.w, fmaf(e1, v1.w, fmaf(e0, v0.w, acc.w))));
        }
        // 2-pair tail (4 edges)
        if (j + 2 <= npair) {
            int b0 = 2 * j + half;
            int s0 = __shfl(myidx, b0 + 0);
            int s1 = __shfl(myidx, b0 + 2);
            float4 v0 = xl4[(size_t)s0 * 32 + hlane];
            float4 v1 = xl4[(size_t)s1 * 32 + hlane];
            float t, p0, p1;
            t = v0.x + xrv.x; t = t > 0.f ? t : 0.2f * t; p0 = t * attv.x;
            t = v0.y + xrv.y; t = t > 0.f ? t : 0.2f * t; p0 = fmaf(t, attv.y, p0);
            t = v0.z + xrv.z; t = t > 0.f ? t : 0.2f * t; p0 = fmaf(t, attv.z, p0);
            t = v0.w + xrv.w; t = t > 0.f ? t : 0.2f * t; p0 = fmaf(t, attv.w, p0);
            t = v1.x + xrv.x; t = t > 0.f ? t : 0.2f * t; p1 = t * attv.x;
            t = v1.y + xrv.y; t = t > 0.f ? t : 0.2f * t; p1 = fmaf(t, attv.y, p1);
            t = v1.z + xrv.z; t = t > 0.f ? t : 0.2f * t; p1 = fmaf(t, attv.z, p1);
            t = v1.w + xrv.w; t = t > 0.f ? t : 0.2f * t; p1 = fmaf(t, attv.w, p1);
            #pragma unroll
            for (int off = 16; off > 0; off >>= 1) {
                p0 += __shfl_xor(p0, off);
                p1 += __shfl_xor(p1, off);
            }
            float e0 = __expf(p0);
            float e1 = __expf(p1);
            dsum += e0 + e1;
            acc.x = fmaf(e1, v1.x, fmaf(e0, v0.x, acc.x));
            acc.y = fmaf(e1, v1.y, fmaf(e0, v0.y, acc.y));
            acc.z = fmaf(e1, v1.z, fmaf(e0, v0.z, acc.z));
            acc.w = fmaf(e1, v1.w, fmaf(e0, v0.w, acc.w));
            j += 2;
        }
        // 1-pair tail
        if (j < npair) {
            int s = __shfl(myidx, 2 * j + half);
            float4 v = xl4[(size_t)s * 32 + hlane];
            float t, p;
            t = v.x + xrv.x; t = t > 0.f ? t : 0.2f * t; p = t * attv.x;
            t = v.y + xrv.y; t = t > 0.f ? t : 0.2f * t; p = fmaf(t, attv.y, p);
            t = v.z + xrv.z; t = t > 0.f ? t : 0.2f * t; p = fmaf(t, attv.z, p);
            t = v.w + xrv.w; t = t > 0.f ? t : 0.2f * t; p = fmaf(t, attv.w, p);
            #pragma unroll
            for (int off = 16; off > 0; off >>= 1) p += __shfl_xor(p, off);
            float e = __expf(p);
            dsum += e;
            acc.x = fmaf(e, v.x, acc.x);
            acc.y = fmaf(e, v.y, acc.y);
            acc.z = fmaf(e, v.z, acc.z);
            acc.w = fmaf(e, v.w, acc.w);
        }
        // odd tail edge: both halves compute; only half 0 accumulates
        if (cnt & 1) {
            int s = __shfl(myidx, cnt - 1);
            float4 v = xl4[(size_t)s * 32 + hlane];
            float t, p;
            t = v.x + xrv.x; t = t > 0.f ? t : 0.2f * t; p = t * attv.x;
            t = v.y + xrv.y; t = t > 0.f ? t : 0.2f * t; p = fmaf(t, attv.y, p);
            t = v.z + xrv.z; t = t > 0.f ? t : 0.2f * t; p = fmaf(t, attv.z, p);
            t = v.w + xrv.w; t = t > 0.f ? t : 0.2f * t; p = fmaf(t, attv.w, p);
            #pragma unroll
            for (int off = 16; off > 0; off >>= 1) p += __shfl_xor(p, off);
            float e = (half == 0) ? __expf(p) : 0.f;
            dsum += e;
            acc.x = fmaf(e, v.x, acc.x);
            acc.y = fmaf(e, v.y, acc.y);
            acc.z = fmaf(e, v.z, acc.z);
            acc.w = fmaf(e, v.w, acc.w);
        }
    }

    dsum += __shfl_xor(dsum, 32);
    acc.x += __shfl_xor(acc.x, 32);
    acc.y += __shfl_xor(acc.y, 32);
    acc.z += __shfl_xor(acc.z, 32);
    acc.w += __shfl_xor(acc.w, 32);

    float inv = dsum > 0.f ? 1.f / dsum : 0.f;
    float4 bv = ((const float4*)bias)[hlane];
    float4 o;
    o.x = acc.x * inv + bv.x;
    o.y = acc.y * inv + bv.y;
    o.z = acc.z * inv + bv.z;
    o.w = acc.w * inv + bv.w;

    if (half == 0) {
        if (emitSplit) {
            float ov[4] = {fmaxf(o.x, 0.f), fmaxf(o.y, 0.f), fmaxf(o.z, 0.f), fmaxf(o.w, 0.f)};
            short hh[4], ll[4];
            #pragma unroll
            for (int j2 = 0; j2 < 4; ++j2) {
                unsigned u = __float_as_uint(ov[j2]);
                unsigned hu = u & 0xFFFF0000u;
                float lf = ov[j2] - __uint_as_float(hu);
                hh[j2] = (short)(hu >> 16);
                ll[j2] = (short)(__float_as_uint(lf) >> 16);
            }
            ((short4*)outHi)[(size_t)node * 32 + hlane] = make_short4(hh[0], hh[1], hh[2], hh[3]);
            ((short4*)outLo)[(size_t)node * 32 + hlane] = make_short4(ll[0], ll[1], ll[2], ll[3]);
        } else {
            ((float4*)outF)[(size_t)node * 32 + hlane] = o;
        }
    }
}

// ---------------------------------------------------------------------------

extern "C" void kernel_launch(void* const* d_in, const int* in_sizes, int n_in,
                              void* d_out, int out_size, void* d_ws, size_t ws_size,
                              hipStream_t stream) {
    const float* x    = (const float*)d_in[0];
    const int* eidx   = (const int*)d_in[1];
    const float* Wl1  = (const float*)d_in[2];
    const float* bl1  = (const float*)d_in[3];
    const float* Wr1  = (const float*)d_in[4];
    const float* br1  = (const float*)d_in[5];
    const float* att1 = (const float*)d_in[6];
    const float* b1   = (const float*)d_in[7];
    const float* Wl2  = (const float*)d_in[8];
    const float* bl2  = (const float*)d_in[9];
    const float* Wr2  = (const float*)d_in[10];
    const float* br2  = (const float*)d_in[11];
    const float* att2 = (const float*)d_in[12];
    const float* b2   = (const float*)d_in[13];

    const int N = in_sizes[0] / 128;
    const int E = in_sizes[1] / 2;
    const int* src = eidx;
    const int* dst = eidx + E;

    // workspace layout
    size_t NF = (size_t)N * 128;
    float* bufA = (float*)d_ws;          // xl (fp32)
    float* bufB = bufA + NF;             // xr (fp32)
    short* Xhi  = (short*)(bufB + NF);   // [N][128] bf16 hi (layer1 in; reused as Hhi)
    short* Xlo  = Xhi + NF;              // [N][128] bf16 lo (reused as Hlo)
    int* deg       = (int*)(Xlo + NF);   // [N+1] (last slot = global counter)
    int* row_beg   = deg + (N + 1);      // [N]
    int* writeidx  = row_beg + N;        // [N]
    int* csr_src   = writeidx + N;       // [E]
    short* wt      = (short*)(csr_src + E);  // 4 matrices x (hi+lo) x 16384

    float* outF = (float*)d_out;

    // --- CSR build (unordered segments) + W/x prep ---
    hipMemsetAsync(deg, 0, (size_t)(N + 1) * sizeof(int), stream);
    prep_w_kernel<<<32, 256, 0, stream>>>(Wl1, Wr1, Wl2, Wr2, wt);
    split_x_kernel<<<(int)((NF / 4 + 255) / 256), 256, 0, stream>>>(x, Xhi, Xlo, (int)(NF / 4));
    count_deg_kernel<<<(E + 255) / 256, 256, 0, stream>>>(dst, deg, E);
    assign_offsets_kernel<<<(N + 255) / 256, 256, 0, stream>>>(deg, row_beg, writeidx, N);
    scatter_edges_kernel<<<(E + 255) / 256, 256, 0, stream>>>(src, dst, writeidx, csr_src, E);

    dim3 gemmGrid((N + 127) / 128, 2);
    dim3 aggGrid((N + 3) / 4);

    // --- layer 1 ---
    gemm_mfma_dual_kernel<<<gemmGrid, 256, 0, stream>>>(Xhi, Xlo, wt, bl1, bufA, br1, bufB, N);
    // aggregate-1 writes h as bf16 hi/lo into Xhi/Xlo (GEMM1 done with them)
    gat_aggregate_kernel<<<aggGrid, 256, 0, stream>>>(bufA, bufB, att1, b1, row_beg, deg,
                                                      csr_src, (float*)0, Xhi, Xlo, N, 1);
    // --- layer 2 ---
    gemm_mfma_dual_kernel<<<gemmGrid, 256, 0, stream>>>(Xhi, Xlo, wt + 2 * 2 * 16384,
                                                        bl2, bufA, br2, bufB, N);
    gat_aggregate_kernel<<<aggGrid, 256, 0, stream>>>(bufA, bufB, att2, b2, row_beg, deg,
                                                      csr_src, outF, (short*)0, (short*)0, N, 0);
}

// Round 9
// 398.837 us; speedup vs baseline: 1.0031x; 1.0031x over previous
//
#include <hip/hip_runtime.h>
#include <math.h>

// ---------------------------------------------------------------------------
// GATv2 2-layer GNN, fp32 in/out. N=50000, E=800000, F=128.
//   1. CSR by dst, UNORDERED segments (memset -> count -> atomic offsets ->
//      scatter)
//   2. prep: W -> bf16 hi/lo transposed [n][k]  +  x -> Xhi/Xlo bf16 (fused)
//   3. GEMM (split-bf16 MFMA 3-term, pre-split staging, wave=128r x 32c)
//   4. aggregate v6 QUARTER-WAVE: each 16-lane quarter holds a full 128-feat
//      row (8 f/lane); 4 edges/step, 2 steps in flight; butterfly = 4 shfl
//      within quarter (vs 5+cross half-wave). DS ops/edge 4 -> ~1.25.
// ---------------------------------------------------------------------------

typedef short bf16x8 __attribute__((ext_vector_type(8)));
typedef float f32x4 __attribute__((ext_vector_type(4)));

__global__ void count_deg_kernel(const int* __restrict__ dst, int* __restrict__ deg, int E) {
    int i = blockIdx.x * blockDim.x + threadIdx.x;
    if (i < E) atomicAdd(&deg[dst[i]], 1);
}

// Each node gets a disjoint contiguous slice [beg, beg+deg) in arbitrary order.
__global__ void assign_offsets_kernel(int* __restrict__ deg, int* __restrict__ row_beg,
                                      int* __restrict__ writeidx, int n) {
    int i = blockIdx.x * blockDim.x + threadIdx.x;
    if (i < n) {
        int d = deg[i];
        int beg = atomicAdd(&deg[n], d);  // wave-aggregated by compiler
        row_beg[i] = beg;
        writeidx[i] = beg;
    }
}

__global__ void scatter_edges_kernel(const int* __restrict__ src, const int* __restrict__ dst,
                                     int* __restrict__ writeidx, int* __restrict__ csr_src, int E) {
    int i = blockIdx.x * blockDim.x + threadIdx.x;
    if (i < E) {
        int d = dst[i];
        int pos = atomicAdd(&writeidx[d], 1);
        csr_src[pos] = src[i];
    }
}

// ---------------------------------------------------------------------------
// Fused prep: blocks 0..31 split the four 128x128 W matrices into bf16 hi/lo
// transposed [n][k]; blocks 32.. split x into Xhi/Xlo bf16 row-major.
// ---------------------------------------------------------------------------
__global__ __launch_bounds__(256) void prep_kernel(
    const float* __restrict__ W0, const float* __restrict__ W1,
    const float* __restrict__ W2, const float* __restrict__ W3,
    short* __restrict__ wt,
    const float* __restrict__ X, short* __restrict__ Xhi, short* __restrict__ Xlo,
    int total4) {
    if (blockIdx.x < 32) {
        int mat = blockIdx.x >> 3;
        int chunk = blockIdx.x & 7;
        const float* W = (mat == 0) ? W0 : (mat == 1) ? W1 : (mat == 2) ? W2 : W3;
        short* hi = wt + (size_t)mat * 2 * 16384;
        short* lo = hi + 16384;
        int i0 = chunk * 2048;
        for (int i = i0 + threadIdx.x; i < i0 + 2048; i += 256) {
            int k = i >> 7, n = i & 127;
            float x = W[i];
            unsigned u = __float_as_uint(x);
            unsigned hu = u & 0xFFFF0000u;
            float lf = x - __uint_as_float(hu);
            hi[n * 128 + k] = (short)(hu >> 16);
            lo[n * 128 + k] = (short)(__float_as_uint(lf) >> 16);
        }
    } else {
        int i = (blockIdx.x - 32) * 256 + threadIdx.x;
        if (i >= total4) return;
        float4 v = ((const float4*)X)[i];
        float vv[4] = {v.x, v.y, v.z, v.w};
        short h[4], l[4];
        #pragma unroll
        for (int j = 0; j < 4; ++j) {
            unsigned u = __float_as_uint(vv[j]);
            unsigned hu = u & 0xFFFF0000u;
            float lf = vv[j] - __uint_as_float(hu);
            h[j] = (short)(hu >> 16);
            l[j] = (short)(__float_as_uint(lf) >> 16);
        }
        ((short4*)Xhi)[i] = make_short4(h[0], h[1], h[2], h[3]);
        ((short4*)Xlo)[i] = make_short4(l[0], l[1], l[2], l[3]);
    }
}

// ---------------------------------------------------------------------------
// Split-bf16 MFMA GEMM (unchanged from round 8): out = X @ W + b.
// ---------------------------------------------------------------------------
__global__ __launch_bounds__(256) void gemm_mfma_dual_kernel(
    const short* __restrict__ Xhi, const short* __restrict__ Xlo,
    const short* __restrict__ wt,
    const float* __restrict__ b0, float* __restrict__ out0,
    const float* __restrict__ b1, float* __restrict__ out1,
    int Nrows) {
    const short* WTh = wt + (size_t)blockIdx.y * 2 * 16384;
    const short* WTl = WTh + 16384;
    const float* bias = blockIdx.y ? b1 : b0;
    float* out = blockIdx.y ? out1 : out0;

    __shared__ short Ahi[128][40];
    __shared__ short Alo[128][40];

    int tid = threadIdx.x;
    int w = tid >> 6, lane = tid & 63, q = lane >> 4, tr = lane & 15;
    int m0 = blockIdx.x * 128;
    int n0 = w * 32;

    f32x4 acc[8][2];
    #pragma unroll
    for (int a = 0; a < 8; ++a)
        #pragma unroll
        for (int b = 0; b < 2; ++b) acc[a][b] = (f32x4){0.f, 0.f, 0.f, 0.f};

    int r0 = tid >> 2;          // 0..63
    int c8 = (tid & 3) * 8;     // 0,8,16,24

    for (int kc = 0; kc < 128; kc += 32) {
        #pragma unroll
        for (int pass = 0; pass < 2; ++pass) {
            int r = r0 + pass * 64;
            int gr = m0 + r; if (gr >= Nrows) gr = Nrows - 1;
            size_t goff = (size_t)gr * 128 + kc + c8;
            bf16x8 vh = *(const bf16x8*)&Xhi[goff];
            bf16x8 vl = *(const bf16x8*)&Xlo[goff];
            *(bf16x8*)&Ahi[r][c8] = vh;
            *(bf16x8*)&Alo[r][c8] = vl;
        }
        __syncthreads();

        bf16x8 bh[2], bl[2];
        #pragma unroll
        for (int nt = 0; nt < 2; ++nt) {
            size_t boff = (size_t)(n0 + nt * 16 + tr) * 128 + kc + q * 8;
            bh[nt] = *(const bf16x8*)&WTh[boff];
            bl[nt] = *(const bf16x8*)&WTl[boff];
        }

        #pragma unroll
        for (int mt = 0; mt < 8; ++mt) {
            bf16x8 ah = *(const bf16x8*)&Ahi[mt * 16 + tr][q * 8];
            bf16x8 al = *(const bf16x8*)&Alo[mt * 16 + tr][q * 8];
            #pragma unroll
            for (int nt = 0; nt < 2; ++nt) {
                acc[mt][nt] = __builtin_amdgcn_mfma_f32_16x16x32_bf16(ah, bh[nt], acc[mt][nt], 0, 0, 0);
                acc[mt][nt] = __builtin_amdgcn_mfma_f32_16x16x32_bf16(ah, bl[nt], acc[mt][nt], 0, 0, 0);
                acc[mt][nt] = __builtin_amdgcn_mfma_f32_16x16x32_bf16(al, bh[nt], acc[mt][nt], 0, 0, 0);
            }
        }
        __syncthreads();
    }

    #pragma unroll
    for (int nt = 0; nt < 2; ++nt) {
        float bv = bias[n0 + nt * 16 + tr];
        #pragma unroll
        for (int mt = 0; mt < 8; ++mt) {
            #pragma unroll
            for (int r = 0; r < 4; ++r) {
                int row = m0 + mt * 16 + q * 4 + r;
                if (row < Nrows)
                    out[(size_t)row * 128 + n0 + nt * 16 + tr] = acc[mt][nt][r] + bv;
            }
        }
    }
}

// ---------------------------------------------------------------------------
// Aggregation v6: QUARTER-WAVE. Each 16-lane quarter holds a full 128-feat
// row (8 floats/lane = 2x float4). 4 edges per step (one per quarter),
// 2 steps in flight; masked tail step. Butterfly = 4 shfl_xor (8,4,2,1)
// within the quarter. Quarter partials combined once at the end.
// emitSplit=1: write bf16 hi/lo (+relu) for the next GEMM.
// ---------------------------------------------------------------------------
__global__ __launch_bounds__(256) void gat_aggregate_kernel(
    const float* __restrict__ xl, const float* __restrict__ xr,
    const float* __restrict__ att, const float* __restrict__ bias,
    const int* __restrict__ row_beg, const int* __restrict__ deg,
    const int* __restrict__ csr_src,
    float* __restrict__ outF, short* __restrict__ outHi, short* __restrict__ outLo,
    int N, int emitSplit) {
    int wid = threadIdx.x >> 6;
    int lane = threadIdx.x & 63;
    int qtr = lane >> 4;   // 0..3
    int ql = lane & 15;    // 0..15
    int node = blockIdx.x * 4 + wid;
    if (node >= N) return;

    const float4* xl4 = (const float4*)xl;
    float4 xra = ((const float4*)xr)[(size_t)node * 32 + ql * 2];
    float4 xrb = ((const float4*)xr)[(size_t)node * 32 + ql * 2 + 1];
    float4 ata = ((const float4*)att)[ql * 2];
    float4 atb = ((const float4*)att)[ql * 2 + 1];

    int beg = row_beg[node];
    int end = beg + deg[node];

    float dsum = 0.f;
    float4 acca = {0.f, 0.f, 0.f, 0.f};
    float4 accb = {0.f, 0.f, 0.f, 0.f};

    for (int cbase = beg; cbase < end; cbase += 64) {
        int cnt = end - cbase;
        if (cnt > 64) cnt = 64;
        int myidx = (lane < cnt) ? csr_src[cbase + lane] : 0;  // coalesced

        int j = 0;
        // --- 2 steps in flight: 8 edges ---
        for (; j + 8 <= cnt; j += 8) {
            int s0 = __shfl(myidx, j + qtr);
            int s1 = __shfl(myidx, j + 4 + qtr);
            float4 v0a = xl4[(size_t)s0 * 32 + ql * 2];
            float4 v0b = xl4[(size_t)s0 * 32 + ql * 2 + 1];
            float4 v1a = xl4[(size_t)s1 * 32 + ql * 2];
            float4 v1b = xl4[(size_t)s1 * 32 + ql * 2 + 1];

            float t, p0, p1;
            t = v0a.x + xra.x; t = t > 0.f ? t : 0.2f * t; p0 = t * ata.x;
            t = v0a.y + xra.y; t = t > 0.f ? t : 0.2f * t; p0 = fmaf(t, ata.y, p0);
            t = v0a.z + xra.z; t = t > 0.f ? t : 0.2f * t; p0 = fmaf(t, ata.z, p0);
            t = v0a.w + xra.w; t = t > 0.f ? t : 0.2f * t; p0 = fmaf(t, ata.w, p0);
            t = v0b.x + xrb.x; t = t > 0.f ? t : 0.2f * t; p0 = fmaf(t, atb.x, p0);
            t = v0b.y + xrb.y; t = t > 0.f ? t : 0.2f * t; p0 = fmaf(t, atb.y, p0);
            t = v0b.z + xrb.z; t = t > 0.f ? t : 0.2f * t; p0 = fmaf(t, atb.z, p0);
            t = v0b.w + xrb.w; t = t > 0.f ? t : 0.2f * t; p0 = fmaf(t, atb.w, p0);
            t = v1a.x + xra.x; t = t > 0.f ? t : 0.2f * t; p1 = t * ata.x;
            t = v1a.y + xra.y; t = t > 0.f ? t : 0.2f * t; p1 = fmaf(t, ata.y, p1);
            t = v1a.z + xra.z; t = t > 0.f ? t : 0.2f * t; p1 = fmaf(t, ata.z, p1);
            t = v1a.w + xra.w; t = t > 0.f ? t : 0.2f * t; p1 = fmaf(t, ata.w, p1);
            t = v1b.x + xrb.x; t = t > 0.f ? t : 0.2f * t; p1 = fmaf(t, atb.x, p1);
            t = v1b.y + xrb.y; t = t > 0.f ? t : 0.2f * t; p1 = fmaf(t, atb.y, p1);
            t = v1b.z + xrb.z; t = t > 0.f ? t : 0.2f * t; p1 = fmaf(t, atb.z, p1);
            t = v1b.w + xrb.w; t = t > 0.f ? t : 0.2f * t; p1 = fmaf(t, atb.w, p1);

            #pragma unroll
            for (int off = 8; off > 0; off >>= 1) {
                p0 += __shfl_xor(p0, off);
                p1 += __shfl_xor(p1, off);
            }

            float e0 = __expf(p0);
            float e1 = __expf(p1);
            dsum += e0 + e1;
            acca.x = fmaf(e1, v1a.x, fmaf(e0, v0a.x, acca.x));
            acca.y = fmaf(e1, v1a.y, fmaf(e0, v0a.y, acca.y));
            acca.z = fmaf(e1, v1a.z, fmaf(e0, v0a.z, acca.z));
            acca.w = fmaf(e1, v1a.w, fmaf(e0, v0a.w, acca.w));
            accb.x = fmaf(e1, v1b.x, fmaf(e0, v0b.x, accb.x));
            accb.y = fmaf(e1, v1b.y, fmaf(e0, v0b.y, accb.y));
            accb.z = fmaf(e1, v1b.z, fmaf(e0, v0b.z, accb.z));
            accb.w = fmaf(e1, v1b.w, fmaf(e0, v0b.w, accb.w));
        }
        // --- masked single-step tail: up to 4 edges per iter ---
        for (; j < cnt; j += 4) {
            int idx = j + qtr;
            int valid = idx < cnt;
            int s = __shfl(myidx, valid ? idx : 0);
            float4 va = xl4[(size_t)s * 32 + ql * 2];
            float4 vb = xl4[(size_t)s * 32 + ql * 2 + 1];
            float t, p;
            t = va.x + xra.x; t = t > 0.f ? t : 0.2f * t; p = t * ata.x;
            t = va.y + xra.y; t = t > 0.f ? t : 0.2f * t; p = fmaf(t, ata.y, p);
            t = va.z + xra.z; t = t > 0.f ? t : 0.2f * t; p = fmaf(t, ata.z, p);
            t = va.w + xra.w; t = t > 0.f ? t : 0.2f * t; p = fmaf(t, ata.w, p);
            t = vb.x + xrb.x; t = t > 0.f ? t : 0.2f * t; p = fmaf(t, atb.x, p);
            t = vb.y + xrb.y; t = t > 0.f ? t : 0.2f * t; p = fmaf(t, atb.y, p);
            t = vb.z + xrb.z; t = t > 0.f ? t : 0.2f * t; p = fmaf(t, atb.z, p);
            t = vb.w + xrb.w; t = t > 0.f ? t : 0.2f * t; p = fmaf(t, atb.w, p);
            #pragma unroll
            for (int off = 8; off > 0; off >>= 1) p += __shfl_xor(p, off);
            float e = valid ? __expf(p) : 0.f;
            dsum += e;
            acca.x = fmaf(e, va.x, acca.x);
            acca.y = fmaf(e, va.y, acca.y);
            acca.z = fmaf(e, va.z, acca.z);
            acca.w = fmaf(e, va.w, acca.w);
            accb.x = fmaf(e, vb.x, accb.x);
            accb.y = fmaf(e, vb.y, accb.y);
            accb.z = fmaf(e, vb.z, accb.z);
            accb.w = fmaf(e, vb.w, accb.w);
        }
    }

    // combine the four quarters (lanes {ql, ql+16, ql+32, ql+48})
    dsum += __shfl_xor(dsum, 16);
    dsum += __shfl_xor(dsum, 32);
    acca.x += __shfl_xor(acca.x, 16); acca.x += __shfl_xor(acca.x, 32);
    acca.y += __shfl_xor(acca.y, 16); acca.y += __shfl_xor(acca.y, 32);
    acca.z += __shfl_xor(acca.z, 16); acca.z += __shfl_xor(acca.z, 32);
    acca.w += __shfl_xor(acca.w, 16); acca.w += __shfl_xor(acca.w, 32);
    accb.x += __shfl_xor(accb.x, 16); accb.x += __shfl_xor(accb.x, 32);
    accb.y += __shfl_xor(accb.y, 16); accb.y += __shfl_xor(accb.y, 32);
    accb.z += __shfl_xor(accb.z, 16); accb.z += __shfl_xor(accb.z, 32);
    accb.w += __shfl_xor(accb.w, 16); accb.w += __shfl_xor(accb.w, 32);

    float inv = dsum > 0.f ? 1.f / dsum : 0.f;
    float4 ba = ((const float4*)bias)[ql * 2];
    float4 bb = ((const float4*)bias)[ql * 2 + 1];
    float4 oa, ob;
    oa.x = acca.x * inv + ba.x; oa.y = acca.y * inv + ba.y;
    oa.z = acca.z * inv + ba.z; oa.w = acca.w * inv + ba.w;
    ob.x = accb.x * inv + bb.x; ob.y = accb.y * inv + bb.y;
    ob.z = accb.z * inv + bb.z; ob.w = accb.w * inv + bb.w;

    if (qtr == 0) {
        if (emitSplit) {
            float ov[8] = {fmaxf(oa.x, 0.f), fmaxf(oa.y, 0.f), fmaxf(oa.z, 0.f), fmaxf(oa.w, 0.f),
                           fmaxf(ob.x, 0.f), fmaxf(ob.y, 0.f), fmaxf(ob.z, 0.f), fmaxf(ob.w, 0.f)};
            short hh[8], ll[8];
            #pragma unroll
            for (int j2 = 0; j2 < 8; ++j2) {
                unsigned u = __float_as_uint(ov[j2]);
                unsigned hu = u & 0xFFFF0000u;
                float lf = ov[j2] - __uint_as_float(hu);
                hh[j2] = (short)(hu >> 16);
                ll[j2] = (short)(__float_as_uint(lf) >> 16);
            }
            ((short4*)outHi)[(size_t)node * 32 + ql * 2]     = make_short4(hh[0], hh[1], hh[2], hh[3]);
            ((short4*)outHi)[(size_t)node * 32 + ql * 2 + 1] = make_short4(hh[4], hh[5], hh[6], hh[7]);
            ((short4*)outLo)[(size_t)node * 32 + ql * 2]     = make_short4(ll[0], ll[1], ll[2], ll[3]);
            ((short4*)outLo)[(size_t)node * 32 + ql * 2 + 1] = make_short4(ll[4], ll[5], ll[6], ll[7]);
        } else {
            ((float4*)outF)[(size_t)node * 32 + ql * 2]     = oa;
            ((float4*)outF)[(size_t)node * 32 + ql * 2 + 1] = ob;
        }
    }
}

// ---------------------------------------------------------------------------

extern "C" void kernel_launch(void* const* d_in, const int* in_sizes, int n_in,
                              void* d_out, int out_size, void* d_ws, size_t ws_size,
                              hipStream_t stream) {
    const float* x    = (const float*)d_in[0];
    const int* eidx   = (const int*)d_in[1];
    const float* Wl1  = (const float*)d_in[2];
    const float* bl1  = (const float*)d_in[3];
    const float* Wr1  = (const float*)d_in[4];
    const float* br1  = (const float*)d_in[5];
    const float* att1 = (const float*)d_in[6];
    const float* b1   = (const float*)d_in[7];
    const float* Wl2  = (const float*)d_in[8];
    const float* bl2  = (const float*)d_in[9];
    const float* Wr2  = (const float*)d_in[10];
    const float* br2  = (const float*)d_in[11];
    const float* att2 = (const float*)d_in[12];
    const float* b2   = (const float*)d_in[13];

    const int N = in_sizes[0] / 128;
    const int E = in_sizes[1] / 2;
    const int* src = eidx;
    const int* dst = eidx + E;

    // workspace layout
    size_t NF = (size_t)N * 128;
    float* bufA = (float*)d_ws;          // xl (fp32)
    float* bufB = bufA + NF;             // xr (fp32)
    short* Xhi  = (short*)(bufB + NF);   // [N][128] bf16 hi (layer1 in; reused as Hhi)
    short* Xlo  = Xhi + NF;              // [N][128] bf16 lo (reused as Hlo)
    int* deg       = (int*)(Xlo + NF);   // [N+1] (last slot = global counter)
    int* row_beg   = deg + (N + 1);      // [N]
    int* writeidx  = row_beg + N;        // [N]
    int* csr_src   = writeidx + N;       // [E]
    short* wt      = (short*)(csr_src + E);  // 4 matrices x (hi+lo) x 16384

    float* outF = (float*)d_out;

    int total4 = (int)(NF / 4);
    int prepGrid = 32 + (total4 + 255) / 256;

    // --- CSR build (unordered segments) + fused W/x prep ---
    hipMemsetAsync(deg, 0, (size_t)(N + 1) * sizeof(int), stream);
    prep_kernel<<<prepGrid, 256, 0, stream>>>(Wl1, Wr1, Wl2, Wr2, wt, x, Xhi, Xlo, total4);
    count_deg_kernel<<<(E + 255) / 256, 256, 0, stream>>>(dst, deg, E);
    assign_offsets_kernel<<<(N + 255) / 256, 256, 0, stream>>>(deg, row_beg, writeidx, N);
    scatter_edges_kernel<<<(E + 255) / 256, 256, 0, stream>>>(src, dst, writeidx, csr_src, E);

    dim3 gemmGrid((N + 127) / 128, 2);
    dim3 aggGrid((N + 3) / 4);

    // --- layer 1 ---
    gemm_mfma_dual_kernel<<<gemmGrid, 256, 0, stream>>>(Xhi, Xlo, wt, bl1, bufA, br1, bufB, N);
    gat_aggregate_kernel<<<aggGrid, 256, 0, stream>>>(bufA, bufB, att1, b1, row_beg, deg,
                                                      csr_src, (float*)0, Xhi, Xlo, N, 1);
    // --- layer 2 ---
    gemm_mfma_dual_kernel<<<gemmGrid, 256, 0, stream>>>(Xhi, Xlo, wt + 2 * 2 * 16384,
                                                        bl2, bufA, br2, bufB, N);
    gat_aggregate_kernel<<<aggGrid, 256, 0, stream>>>(bufA, bufB, att2, b2, row_beg, deg,
                                                      csr_src, outF, (short*)0, (short*)0, N, 0);
}

// Round 10
// 387.739 us; speedup vs baseline: 1.0318x; 1.0286x over previous
//
#include <hip/hip_runtime.h>
#include <math.h>

// ---------------------------------------------------------------------------
// GATv2 2-layer GNN, fp32 in/out. N=50000, E=800000, F=128.
//   1. CSR by dst, UNORDERED segments (memset -> count -> atomic offsets ->
//      scatter)
//   2. prep: W -> bf16 hi/lo transposed [n][k]; x -> Xhi/Xlo bf16 (fused)
//   3. GEMM (split-bf16 MFMA 3-term): xl output emitted as bf16 RNE
//      (messages), xr output fp32 (read-once).
//   4. aggregate (round-7 half-wave core): gathers 256 B bf16 rows instead
//      of 512 B fp32 — halves L2-miss traffic of the gather stream.
// ---------------------------------------------------------------------------

typedef short bf16x8 __attribute__((ext_vector_type(8)));
typedef float f32x4 __attribute__((ext_vector_type(4)));

__device__ inline unsigned short f32_to_bf16_rne(float v) {
    unsigned u = __float_as_uint(v);
    return (unsigned short)((u + 0x7FFFu + ((u >> 16) & 1u)) >> 16);
}

__device__ inline float4 bf4_to_f4(ushort4 u) {
    float4 r;
    r.x = __uint_as_float((unsigned)u.x << 16);
    r.y = __uint_as_float((unsigned)u.y << 16);
    r.z = __uint_as_float((unsigned)u.z << 16);
    r.w = __uint_as_float((unsigned)u.w << 16);
    return r;
}

__global__ void count_deg_kernel(const int* __restrict__ dst, int* __restrict__ deg, int E) {
    int i = blockIdx.x * blockDim.x + threadIdx.x;
    if (i < E) atomicAdd(&deg[dst[i]], 1);
}

__global__ void assign_offsets_kernel(int* __restrict__ deg, int* __restrict__ row_beg,
                                      int* __restrict__ writeidx, int n) {
    int i = blockIdx.x * blockDim.x + threadIdx.x;
    if (i < n) {
        int d = deg[i];
        int beg = atomicAdd(&deg[n], d);  // wave-aggregated by compiler
        row_beg[i] = beg;
        writeidx[i] = beg;
    }
}

__global__ void scatter_edges_kernel(const int* __restrict__ src, const int* __restrict__ dst,
                                     int* __restrict__ writeidx, int* __restrict__ csr_src, int E) {
    int i = blockIdx.x * blockDim.x + threadIdx.x;
    if (i < E) {
        int d = dst[i];
        int pos = atomicAdd(&writeidx[d], 1);
        csr_src[pos] = src[i];
    }
}

// ---------------------------------------------------------------------------
// Fused prep: blocks 0..31 split W matrices into bf16 hi/lo transposed [n][k];
// blocks 32.. split x into Xhi/Xlo bf16 row-major.
// ---------------------------------------------------------------------------
__global__ __launch_bounds__(256) void prep_kernel(
    const float* __restrict__ W0, const float* __restrict__ W1,
    const float* __restrict__ W2, const float* __restrict__ W3,
    short* __restrict__ wt,
    const float* __restrict__ X, short* __restrict__ Xhi, short* __restrict__ Xlo,
    int total4) {
    if (blockIdx.x < 32) {
        int mat = blockIdx.x >> 3;
        int chunk = blockIdx.x & 7;
        const float* W = (mat == 0) ? W0 : (mat == 1) ? W1 : (mat == 2) ? W2 : W3;
        short* hi = wt + (size_t)mat * 2 * 16384;
        short* lo = hi + 16384;
        int i0 = chunk * 2048;
        for (int i = i0 + threadIdx.x; i < i0 + 2048; i += 256) {
            int k = i >> 7, n = i & 127;
            float x = W[i];
            unsigned u = __float_as_uint(x);
            unsigned hu = u & 0xFFFF0000u;
            float lf = x - __uint_as_float(hu);
            hi[n * 128 + k] = (short)(hu >> 16);
            lo[n * 128 + k] = (short)(__float_as_uint(lf) >> 16);
        }
    } else {
        int i = (blockIdx.x - 32) * 256 + threadIdx.x;
        if (i >= total4) return;
        float4 v = ((const float4*)X)[i];
        float vv[4] = {v.x, v.y, v.z, v.w};
        short h[4], l[4];
        #pragma unroll
        for (int j = 0; j < 4; ++j) {
            unsigned u = __float_as_uint(vv[j]);
            unsigned hu = u & 0xFFFF0000u;
            float lf = vv[j] - __uint_as_float(hu);
            h[j] = (short)(hu >> 16);
            l[j] = (short)(__float_as_uint(lf) >> 16);
        }
        ((short4*)Xhi)[i] = make_short4(h[0], h[1], h[2], h[3]);
        ((short4*)Xlo)[i] = make_short4(l[0], l[1], l[2], l[3]);
    }
}

// ---------------------------------------------------------------------------
// Split-bf16 MFMA GEMM: {xl(bf16), xr(fp32)} = X @ {Wl, Wr} + {bl, br}.
// blockIdx.y==0 -> Wl product, epilogue emits bf16 RNE (message matrix).
// blockIdx.y==1 -> Wr product, epilogue emits fp32.
// ---------------------------------------------------------------------------
__global__ __launch_bounds__(256) void gemm_mfma_dual_kernel(
    const short* __restrict__ Xhi, const short* __restrict__ Xlo,
    const short* __restrict__ wt,
    const float* __restrict__ b0, unsigned short* __restrict__ outBf,
    const float* __restrict__ b1, float* __restrict__ outF,
    int Nrows) {
    const short* WTh = wt + (size_t)blockIdx.y * 2 * 16384;
    const short* WTl = WTh + 16384;
    const float* bias = blockIdx.y ? b1 : b0;

    __shared__ short Ahi[128][40];
    __shared__ short Alo[128][40];

    int tid = threadIdx.x;
    int w = tid >> 6, lane = tid & 63, q = lane >> 4, tr = lane & 15;
    int m0 = blockIdx.x * 128;
    int n0 = w * 32;

    f32x4 acc[8][2];
    #pragma unroll
    for (int a = 0; a < 8; ++a)
        #pragma unroll
        for (int b = 0; b < 2; ++b) acc[a][b] = (f32x4){0.f, 0.f, 0.f, 0.f};

    int r0 = tid >> 2;          // 0..63
    int c8 = (tid & 3) * 8;     // 0,8,16,24

    for (int kc = 0; kc < 128; kc += 32) {
        #pragma unroll
        for (int pass = 0; pass < 2; ++pass) {
            int r = r0 + pass * 64;
            int gr = m0 + r; if (gr >= Nrows) gr = Nrows - 1;
            size_t goff = (size_t)gr * 128 + kc + c8;
            bf16x8 vh = *(const bf16x8*)&Xhi[goff];
            bf16x8 vl = *(const bf16x8*)&Xlo[goff];
            *(bf16x8*)&Ahi[r][c8] = vh;
            *(bf16x8*)&Alo[r][c8] = vl;
        }
        __syncthreads();

        bf16x8 bh[2], bl[2];
        #pragma unroll
        for (int nt = 0; nt < 2; ++nt) {
            size_t boff = (size_t)(n0 + nt * 16 + tr) * 128 + kc + q * 8;
            bh[nt] = *(const bf16x8*)&WTh[boff];
            bl[nt] = *(const bf16x8*)&WTl[boff];
        }

        #pragma unroll
        for (int mt = 0; mt < 8; ++mt) {
            bf16x8 ah = *(const bf16x8*)&Ahi[mt * 16 + tr][q * 8];
            bf16x8 al = *(const bf16x8*)&Alo[mt * 16 + tr][q * 8];
            #pragma unroll
            for (int nt = 0; nt < 2; ++nt) {
                acc[mt][nt] = __builtin_amdgcn_mfma_f32_16x16x32_bf16(ah, bh[nt], acc[mt][nt], 0, 0, 0);
                acc[mt][nt] = __builtin_amdgcn_mfma_f32_16x16x32_bf16(ah, bl[nt], acc[mt][nt], 0, 0, 0);
                acc[mt][nt] = __builtin_amdgcn_mfma_f32_16x16x32_bf16(al, bh[nt], acc[mt][nt], 0, 0, 0);
            }
        }
        __syncthreads();
    }

    // epilogue: D layout col = lane&15, row = q*4 + reg
    #pragma unroll
    for (int nt = 0; nt < 2; ++nt) {
        float bv = bias[n0 + nt * 16 + tr];
        #pragma unroll
        for (int mt = 0; mt < 8; ++mt) {
            #pragma unroll
            for (int r = 0; r < 4; ++r) {
                int row = m0 + mt * 16 + q * 4 + r;
                if (row < Nrows) {
                    float v = acc[mt][nt][r] + bv;
                    size_t off = (size_t)row * 128 + n0 + nt * 16 + tr;
                    if (blockIdx.y == 0) outBf[off] = f32_to_bf16_rne(v);
                    else                 outF[off] = v;
                }
            }
        }
    }
}

// ---------------------------------------------------------------------------
// Aggregation (round-7 half-wave core, bf16 message gathers): plain-exp
// softmax, 4-pair batches (8 edges in flight) + 2/1-pair tails. Each lane
// loads ushort4 (8 B) per edge -> 256 B/row vs 512 fp32.
// emitSplit=1: write h as bf16 hi/lo (+relu) for the next GEMM.
// ---------------------------------------------------------------------------
__global__ __launch_bounds__(256) void gat_aggregate_kernel(
    const unsigned short* __restrict__ xlb, const float* __restrict__ xr,
    const float* __restrict__ att, const float* __restrict__ bias,
    const int* __restrict__ row_beg, const int* __restrict__ deg,
    const int* __restrict__ csr_src,
    float* __restrict__ outF, short* __restrict__ outHi, short* __restrict__ outLo,
    int N, int emitSplit) {
    int wid = threadIdx.x >> 6;
    int lane = threadIdx.x & 63;
    int hlane = lane & 31;
    int half = lane >> 5;
    int node = blockIdx.x * 4 + wid;
    if (node >= N) return;

    const ushort4* xl4 = (const ushort4*)xlb;   // row = 32 x ushort4
    float4 xrv = ((const float4*)xr)[(size_t)node * 32 + hlane];
    float4 attv = ((const float4*)att)[hlane];

    int beg = row_beg[node];
    int end = beg + deg[node];

    float dsum = 0.f;
    float4 acc = {0.f, 0.f, 0.f, 0.f};

    for (int cbase = beg; cbase < end; cbase += 64) {
        int cnt = end - cbase;
        if (cnt > 64) cnt = 64;
        int myidx = (lane < cnt) ? csr_src[cbase + lane] : 0;  // coalesced
        int npair = cnt >> 1;

        int j = 0;
        for (; j + 4 <= npair; j += 4) {
            int b0 = 2 * j + half;
            int s0 = __shfl(myidx, b0 + 0);
            int s1 = __shfl(myidx, b0 + 2);
            int s2 = __shfl(myidx, b0 + 4);
            int s3 = __shfl(myidx, b0 + 6);
            float4 v0 = bf4_to_f4(xl4[(size_t)s0 * 32 + hlane]);
            float4 v1 = bf4_to_f4(xl4[(size_t)s1 * 32 + hlane]);
            float4 v2 = bf4_to_f4(xl4[(size_t)s2 * 32 + hlane]);
            float4 v3 = bf4_to_f4(xl4[(size_t)s3 * 32 + hlane]);

            float t, p0, p1, p2, p3;
            t = v0.x + xrv.x; t = t > 0.f ? t : 0.2f * t; p0 = t * attv.x;
            t = v0.y + xrv.y; t = t > 0.f ? t : 0.2f * t; p0 = fmaf(t, attv.y, p0);
            t = v0.z + xrv.z; t = t > 0.f ? t : 0.2f * t; p0 = fmaf(t, attv.z, p0);
            t = v0.w + xrv.w; t = t > 0.f ? t : 0.2f * t; p0 = fmaf(t, attv.w, p0);
            t = v1.x + xrv.x; t = t > 0.f ? t : 0.2f * t; p1 = t * attv.x;
            t = v1.y + xrv.y; t = t > 0.f ? t : 0.2f * t; p1 = fmaf(t, attv.y, p1);
            t = v1.z + xrv.z; t = t > 0.f ? t : 0.2f * t; p1 = fmaf(t, attv.z, p1);
            t = v1.w + xrv.w; t = t > 0.f ? t : 0.2f * t; p1 = fmaf(t, attv.w, p1);
            t = v2.x + xrv.x; t = t > 0.f ? t : 0.2f * t; p2 = t * attv.x;
            t = v2.y + xrv.y; t = t > 0.f ? t : 0.2f * t; p2 = fmaf(t, attv.y, p2);
            t = v2.z + xrv.z; t = t > 0.f ? t : 0.2f * t; p2 = fmaf(t, attv.z, p2);
            t = v2.w + xrv.w; t = t > 0.f ? t : 0.2f * t; p2 = fmaf(t, attv.w, p2);
            t = v3.x + xrv.x; t = t > 0.f ? t : 0.2f * t; p3 = t * attv.x;
            t = v3.y + xrv.y; t = t > 0.f ? t : 0.2f * t; p3 = fmaf(t, attv.y, p3);
            t = v3.z + xrv.z; t = t > 0.f ? t : 0.2f * t; p3 = fmaf(t, attv.z, p3);
            t = v3.w + xrv.w; t = t > 0.f ? t : 0.2f * t; p3 = fmaf(t, attv.w, p3);

            #pragma unroll
            for (int off = 16; off > 0; off >>= 1) {
                p0 += __shfl_xor(p0, off);
                p1 += __shfl_xor(p1, off);
                p2 += __shfl_xor(p2, off);
                p3 += __shfl_xor(p3, off);
            }

            float e0 = __expf(p0);
            float e1 = __expf(p1);
            float e2 = __expf(p2);
            float e3 = __expf(p3);
            dsum += (e0 + e1) + (e2 + e3);
            acc.x = fmaf(e3, v3.x, fmaf(e2, v2.x, fmaf(e1, v1.x, fmaf(e0, v0.x, acc.x))));
            acc.y = fmaf(e3, v3.y, fmaf(e2, v2.y, fmaf(e1, v1.y, fmaf(e0, v0.y, acc.y))));
            acc.z = fmaf(e3, v3.z, fmaf(e2, v2.z, fmaf(e1, v1.z, fmaf(e0, v0.z, acc.z))));
            acc.w = fmaf(e3, v3.w, fmaf(e2, v2.w, fmaf(e1, v1.w, fmaf(e0, v0.w, acc.w))));
        }
        // 2-pair tail (4 edges)
        if (j + 2 <= npair) {
            int b0 = 2 * j + half;
            int s0 = __shfl(myidx, b0 + 0);
            int s1 = __shfl(myidx, b0 + 2);
            float4 v0 = bf4_to_f4(xl4[(size_t)s0 * 32 + hlane]);
            float4 v1 = bf4_to_f4(xl4[(size_t)s1 * 32 + hlane]);
            float t, p0, p1;
            t = v0.x + xrv.x; t = t > 0.f ? t : 0.2f * t; p0 = t * attv.x;
            t = v0.y + xrv.y; t = t > 0.f ? t : 0.2f * t; p0 = fmaf(t, attv.y, p0);
            t = v0.z + xrv.z; t = t > 0.f ? t : 0.2f * t; p0 = fmaf(t, attv.z, p0);
            t = v0.w + xrv.w; t = t > 0.f ? t : 0.2f * t; p0 = fmaf(t, attv.w, p0);
            t = v1.x + xrv.x; t = t > 0.f ? t : 0.2f * t; p1 = t * attv.x;
            t = v1.y + xrv.y; t = t > 0.f ? t : 0.2f * t; p1 = fmaf(t, attv.y, p1);
            t = v1.z + xrv.z; t = t > 0.f ? t : 0.2f * t; p1 = fmaf(t, attv.z, p1);
            t = v1.w + xrv.w; t = t > 0.f ? t : 0.2f * t; p1 = fmaf(t, attv.w, p1);
            #pragma unroll
            for (int off = 16; off > 0; off >>= 1) {
                p0 += __shfl_xor(p0, off);
                p1 += __shfl_xor(p1, off);
            }
            float e0 = __expf(p0);
            float e1 = __expf(p1);
            dsum += e0 + e1;
            acc.x = fmaf(e1, v1.x, fmaf(e0, v0.x, acc.x));
            acc.y = fmaf(e1, v1.y, fmaf(e0, v0.y, acc.y));
            acc.z = fmaf(e1, v1.z, fmaf(e0, v0.z, acc.z));
            acc.w = fmaf(e1, v1.w, fmaf(e0, v0.w, acc.w));
            j += 2;
        }
        // 1-pair tail
        if (j < npair) {
            int s = __shfl(myidx, 2 * j + half);
            float4 v = bf4_to_f4(xl4[(size_t)s * 32 + hlane]);
            float t, p;
            t = v.x + xrv.x; t = t > 0.f ? t : 0.2f * t; p = t * attv.x;
            t = v.y + xrv.y; t = t > 0.f ? t : 0.2f * t; p = fmaf(t, attv.y, p);
            t = v.z + xrv.z; t = t > 0.f ? t : 0.2f * t; p = fmaf(t, attv.z, p);
            t = v.w + xrv.w; t = t > 0.f ? t : 0.2f * t; p = fmaf(t, attv.w, p);
            #pragma unroll
            for (int off = 16; off > 0; off >>= 1) p += __shfl_xor(p, off);
            float e = __expf(p);
            dsum += e;
            acc.x = fmaf(e, v.x, acc.x);
            acc.y = fmaf(e, v.y, acc.y);
            acc.z = fmaf(e, v.z, acc.z);
            acc.w = fmaf(e, v.w, acc.w);
        }
        // odd tail edge: both halves compute; only half 0 accumulates
        if (cnt & 1) {
            int s = __shfl(myidx, cnt - 1);
            float4 v = bf4_to_f4(xl4[(size_t)s * 32 + hlane]);
            float t, p;
            t = v.x + xrv.x; t = t > 0.f ? t : 0.2f * t; p = t * attv.x;
            t = v.y + xrv.y; t = t > 0.f ? t : 0.2f * t; p = fmaf(t, attv.y, p);
            t = v.z + xrv.z; t = t > 0.f ? t : 0.2f * t; p = fmaf(t, attv.z, p);
            t = v.w + xrv.w; t = t > 0.f ? t : 0.2f * t; p = fmaf(t, attv.w, p);
            #pragma unroll
            for (int off = 16; off > 0; off >>= 1) p += __shfl_xor(p, off);
            float e = (half == 0) ? __expf(p) : 0.f;
            dsum += e;
            acc.x = fmaf(e, v.x, acc.x);
            acc.y = fmaf(e, v.y, acc.y);
            acc.z = fmaf(e, v.z, acc.z);
            acc.w = fmaf(e, v.w, acc.w);
        }
    }

    dsum += __shfl_xor(dsum, 32);
    acc.x += __shfl_xor(acc.x, 32);
    acc.y += __shfl_xor(acc.y, 32);
    acc.z += __shfl_xor(acc.z, 32);
    acc.w += __shfl_xor(acc.w, 32);

    float inv = dsum > 0.f ? 1.f / dsum : 0.f;
    float4 bv = ((const float4*)bias)[hlane];
    float4 o;
    o.x = acc.x * inv + bv.x;
    o.y = acc.y * inv + bv.y;
    o.z = acc.z * inv + bv.z;
    o.w = acc.w * inv + bv.w;

    if (half == 0) {
        if (emitSplit) {
            float ov[4] = {fmaxf(o.x, 0.f), fmaxf(o.y, 0.f), fmaxf(o.z, 0.f), fmaxf(o.w, 0.f)};
            short hh[4], ll[4];
            #pragma unroll
            for (int j2 = 0; j2 < 4; ++j2) {
                unsigned u = __float_as_uint(ov[j2]);
                unsigned hu = u & 0xFFFF0000u;
                float lf = ov[j2] - __uint_as_float(hu);
                hh[j2] = (short)(hu >> 16);
                ll[j2] = (short)(__float_as_uint(lf) >> 16);
            }
            ((short4*)outHi)[(size_t)node * 32 + hlane] = make_short4(hh[0], hh[1], hh[2], hh[3]);
            ((short4*)outLo)[(size_t)node * 32 + hlane] = make_short4(ll[0], ll[1], ll[2], ll[3]);
        } else {
            ((float4*)outF)[(size_t)node * 32 + hlane] = o;
        }
    }
}

// ---------------------------------------------------------------------------

extern "C" void kernel_launch(void* const* d_in, const int* in_sizes, int n_in,
                              void* d_out, int out_size, void* d_ws, size_t ws_size,
                              hipStream_t stream) {
    const float* x    = (const float*)d_in[0];
    const int* eidx   = (const int*)d_in[1];
    const float* Wl1  = (const float*)d_in[2];
    const float* bl1  = (const float*)d_in[3];
    const float* Wr1  = (const float*)d_in[4];
    const float* br1  = (const float*)d_in[5];
    const float* att1 = (const float*)d_in[6];
    const float* b1   = (const float*)d_in[7];
    const float* Wl2  = (const float*)d_in[8];
    const float* bl2  = (const float*)d_in[9];
    const float* Wr2  = (const float*)d_in[10];
    const float* br2  = (const float*)d_in[11];
    const float* att2 = (const float*)d_in[12];
    const float* b2   = (const float*)d_in[13];

    const int N = in_sizes[0] / 128;
    const int E = in_sizes[1] / 2;
    const int* src = eidx;
    const int* dst = eidx + E;

    // workspace layout
    size_t NF = (size_t)N * 128;
    unsigned short* xlBf = (unsigned short*)d_ws;   // [N][128] bf16 messages
    float* bufB = (float*)(xlBf + NF);              // xr (fp32)
    short* Xhi  = (short*)(bufB + NF);              // [N][128] bf16 hi (x, then h)
    short* Xlo  = Xhi + NF;                         // [N][128] bf16 lo
    int* deg       = (int*)(Xlo + NF);              // [N+1] (last = counter)
    int* row_beg   = deg + (N + 1);
    int* writeidx  = row_beg + N;
    int* csr_src   = writeidx + N;                  // [E]
    short* wt      = (short*)(csr_src + E);         // 4 x (hi+lo) x 16384

    float* outF = (float*)d_out;

    int total4 = (int)(NF / 4);
    int prepGrid = 32 + (total4 + 255) / 256;

    // --- CSR build (unordered segments) + fused W/x prep ---
    hipMemsetAsync(deg, 0, (size_t)(N + 1) * sizeof(int), stream);
    prep_kernel<<<prepGrid, 256, 0, stream>>>(Wl1, Wr1, Wl2, Wr2, wt, x, Xhi, Xlo, total4);
    count_deg_kernel<<<(E + 255) / 256, 256, 0, stream>>>(dst, deg, E);
    assign_offsets_kernel<<<(N + 255) / 256, 256, 0, stream>>>(deg, row_beg, writeidx, N);
    scatter_edges_kernel<<<(E + 255) / 256, 256, 0, stream>>>(src, dst, writeidx, csr_src, E);

    dim3 gemmGrid((N + 127) / 128, 2);
    dim3 aggGrid((N + 3) / 4);

    // --- layer 1 ---
    gemm_mfma_dual_kernel<<<gemmGrid, 256, 0, stream>>>(Xhi, Xlo, wt, bl1, xlBf, br1, bufB, N);
    gat_aggregate_kernel<<<aggGrid, 256, 0, stream>>>(xlBf, bufB, att1, b1, row_beg, deg,
                                                      csr_src, (float*)0, Xhi, Xlo, N, 1);
    // --- layer 2 ---
    gemm_mfma_dual_kernel<<<gemmGrid, 256, 0, stream>>>(Xhi, Xlo, wt + 2 * 2 * 16384,
                                                        bl2, xlBf, br2, bufB, N);
    gat_aggregate_kernel<<<aggGrid, 256, 0, stream>>>(xlBf, bufB, att2, b2, row_beg, deg,
                                                      csr_src, outF, (short*)0, (short*)0, N, 0);
}